// Round 3
// baseline (1373.816 us; speedup 1.0000x reference)
//
#include <hip/hip_runtime.h>

// Fused: linear(12->1)+tanh -> LSTM(1->7) -> LSTM(7->7) -> linear(14->1)
// Round 3 = Round 2 resubmit (infra failure, no signal): all weights staged
// to LDS once per block, transposed so the hidden-matvec inner loops read
// broadcast ds_read_b128 (28 = 7 x float4). Biases pre-combined. 1-deep
// prefetch on x. One thread per batch element.

static __device__ __forceinline__ float fexp2(float x) { return __builtin_amdgcn_exp2f(x); }
static __device__ __forceinline__ float frcp(float x)  { return __builtin_amdgcn_rcpf(x); }
static __device__ __forceinline__ float sigm(float x)  {
    return frcp(1.0f + fexp2(-1.4426950408889634f * x));
}
static __device__ __forceinline__ float tanhh(float x) {
    return 1.0f - 2.0f * frcp(fexp2(2.8853900817779268f * x) + 1.0f);
}

#define TT 14
#define FF 12
#define HH 7
#define NG 28   // 4*HH gate rows, r = gate*7 + j  (i,f,g,o)

// LDS float-index offsets (all multiples of 4 -> 16B aligned)
#define OFF_W1    0     // 12 floats (+4 pad)
#define OFF_WIH0  16    // 28
#define OFF_B0    44    // 28 (bih0+bhh0)
#define OFF_WHH0  72    // 196, transposed: [k][r] = whh0[r*7+k]
#define OFF_WIH1  268   // 196, transposed
#define OFF_WHH1  464   // 196, transposed
#define OFF_B1    660   // 28 (bih1+bhh1)
#define OFF_W2    688   // 14
#define OFF_SC    702   // b1, b2 scalars
#define SMEM_F    704

#define LD4(off) (*reinterpret_cast<const float4*>(sm + (off)))

__global__ __launch_bounds__(256)
void lstm_fused_kernel(const float* __restrict__ x,
                       const float* __restrict__ w1,   const float* __restrict__ b1,
                       const float* __restrict__ wih0, const float* __restrict__ whh0,
                       const float* __restrict__ bih0, const float* __restrict__ bhh0,
                       const float* __restrict__ wih1, const float* __restrict__ whh1,
                       const float* __restrict__ bih1, const float* __restrict__ bhh1,
                       const float* __restrict__ w2,   const float* __restrict__ b2,
                       float* __restrict__ out, int Bn)
{
    __shared__ __align__(16) float sm[SMEM_F];
    const int tid = threadIdx.x;

    // ---- stage weights to LDS (transpose hidden matrices to [k][r]) ----
    if (tid < 196) { int k = tid / 28, r = tid % 28; sm[OFF_WHH0 + tid] = whh0[r * 7 + k]; }
    if (tid < 196) { int k = tid / 28, r = tid % 28; sm[OFF_WIH1 + tid] = wih1[r * 7 + k]; }
    if (tid < 196) { int k = tid / 28, r = tid % 28; sm[OFF_WHH1 + tid] = whh1[r * 7 + k]; }
    if (tid < NG) {
        sm[OFF_WIH0 + tid] = wih0[tid];
        sm[OFF_B0 + tid]   = bih0[tid] + bhh0[tid];
        sm[OFF_B1 + tid]   = bih1[tid] + bhh1[tid];
    }
    if (tid < FF)      sm[OFF_W1 + tid] = w1[tid];
    if (tid < 2 * HH)  sm[OFF_W2 + tid] = w2[tid];
    if (tid == 0) { sm[OFF_SC] = b1[0]; sm[OFF_SC + 1] = b2[0]; }
    __syncthreads();

    const int b = blockIdx.x * blockDim.x + tid;
    if (b >= Bn) return;
    const float4* xv = reinterpret_cast<const float4*>(x + (size_t)b * (TT * FF));

    float h0[HH], c0[HH], h1[HH], c1[HH];
#pragma unroll
    for (int j = 0; j < HH; ++j) { h0[j] = 0.f; c0[j] = 0.f; h1[j] = 0.f; c1[j] = 0.f; }

    const float b1s = sm[OFF_SC], b2s = sm[OFF_SC + 1];
    float4 xr0 = xv[0], xr1 = xv[1], xr2 = xv[2];

#pragma unroll 1
    for (int t = 0; t < TT; ++t) {
        // prefetch next timestep's x (wraps to 0 on last iter; always in-bounds)
        const int tn = (t < TT - 1) ? 3 * (t + 1) : 0;
        float4 na = xv[tn], nb = xv[tn + 1], nc = xv[tn + 2];

        // ---- linear_1 + tanh ----
        float acc = b1s;
        {
            float4 wa = LD4(OFF_W1 + 0), wb = LD4(OFF_W1 + 4), wc = LD4(OFF_W1 + 8);
            acc = fmaf(xr0.x, wa.x, acc); acc = fmaf(xr0.y, wa.y, acc);
            acc = fmaf(xr0.z, wa.z, acc); acc = fmaf(xr0.w, wa.w, acc);
            acc = fmaf(xr1.x, wb.x, acc); acc = fmaf(xr1.y, wb.y, acc);
            acc = fmaf(xr1.z, wb.z, acc); acc = fmaf(xr1.w, wb.w, acc);
            acc = fmaf(xr2.x, wc.x, acc); acc = fmaf(xr2.y, wc.y, acc);
            acc = fmaf(xr2.z, wc.z, acc); acc = fmaf(xr2.w, wc.w, acc);
        }
        const float xt = tanhh(acc);

        float z[NG];

        // ---- LSTM layer 0: z = b0 + xt*wih0 + h0 @ whh0^T ----
#pragma unroll
        for (int q = 0; q < 7; ++q) {
            float4 bq = LD4(OFF_B0 + 4 * q);
            float4 wq = LD4(OFF_WIH0 + 4 * q);
            z[4*q+0] = fmaf(xt, wq.x, bq.x);
            z[4*q+1] = fmaf(xt, wq.y, bq.y);
            z[4*q+2] = fmaf(xt, wq.z, bq.z);
            z[4*q+3] = fmaf(xt, wq.w, bq.w);
        }
#pragma unroll
        for (int k = 0; k < HH; ++k) {
            const float hk = h0[k];
#pragma unroll
            for (int q = 0; q < 7; ++q) {
                float4 wq = LD4(OFF_WHH0 + 28 * k + 4 * q);
                z[4*q+0] = fmaf(hk, wq.x, z[4*q+0]);
                z[4*q+1] = fmaf(hk, wq.y, z[4*q+1]);
                z[4*q+2] = fmaf(hk, wq.z, z[4*q+2]);
                z[4*q+3] = fmaf(hk, wq.w, z[4*q+3]);
            }
        }
#pragma unroll
        for (int j = 0; j < HH; ++j) {
            const float ii = sigm(z[j]);
            const float ff = sigm(z[HH + j]);
            const float gg = tanhh(z[2 * HH + j]);
            const float oo = sigm(z[3 * HH + j]);
            c0[j] = ff * c0[j] + ii * gg;
            h0[j] = oo * tanhh(c0[j]);
        }

        // ---- LSTM layer 1: z = b1 + h0 @ wih1^T + h1 @ whh1^T ----
#pragma unroll
        for (int q = 0; q < 7; ++q) {
            float4 bq = LD4(OFF_B1 + 4 * q);
            z[4*q+0] = bq.x; z[4*q+1] = bq.y; z[4*q+2] = bq.z; z[4*q+3] = bq.w;
        }
#pragma unroll
        for (int k = 0; k < HH; ++k) {
            const float hk = h0[k];   // new h0 = layer-1 input
            const float gk = h1[k];
#pragma unroll
            for (int q = 0; q < 7; ++q) {
                float4 wq = LD4(OFF_WIH1 + 28 * k + 4 * q);
                float4 vq = LD4(OFF_WHH1 + 28 * k + 4 * q);
                z[4*q+0] = fmaf(hk, wq.x, fmaf(gk, vq.x, z[4*q+0]));
                z[4*q+1] = fmaf(hk, wq.y, fmaf(gk, vq.y, z[4*q+1]));
                z[4*q+2] = fmaf(hk, wq.z, fmaf(gk, vq.z, z[4*q+2]));
                z[4*q+3] = fmaf(hk, wq.w, fmaf(gk, vq.w, z[4*q+3]));
            }
        }
#pragma unroll
        for (int j = 0; j < HH; ++j) {
            const float ii = sigm(z[j]);
            const float ff = sigm(z[HH + j]);
            const float gg = tanhh(z[2 * HH + j]);
            const float oo = sigm(z[3 * HH + j]);
            c1[j] = ff * c1[j] + ii * gg;
            h1[j] = oo * tanhh(c1[j]);
        }

        xr0 = na; xr1 = nb; xr2 = nc;
    }

    // ---- linear_2 on concat(h0_final, h1_final) ----
    float r = b2s;
#pragma unroll
    for (int j = 0; j < HH; ++j) r = fmaf(h0[j], sm[OFF_W2 + j], r);
#pragma unroll
    for (int j = 0; j < HH; ++j) r = fmaf(h1[j], sm[OFF_W2 + HH + j], r);
    out[b] = r;
}

extern "C" void kernel_launch(void* const* d_in, const int* in_sizes, int n_in,
                              void* d_out, int out_size, void* d_ws, size_t ws_size,
                              hipStream_t stream)
{
    const float* x    = (const float*)d_in[0];
    const float* w1   = (const float*)d_in[1];
    const float* b1   = (const float*)d_in[2];
    const float* wih0 = (const float*)d_in[3];
    const float* whh0 = (const float*)d_in[4];
    const float* bih0 = (const float*)d_in[5];
    const float* bhh0 = (const float*)d_in[6];
    const float* wih1 = (const float*)d_in[7];
    const float* whh1 = (const float*)d_in[8];
    const float* bih1 = (const float*)d_in[9];
    const float* bhh1 = (const float*)d_in[10];
    const float* w2   = (const float*)d_in[11];
    const float* b2   = (const float*)d_in[12];
    float* out = (float*)d_out;

    const int Bn = in_sizes[0] / (TT * FF);
    dim3 grid((Bn + 255) / 256), block(256);
    hipLaunchKernelGGL(lstm_fused_kernel, grid, block, 0, stream,
                       x, w1, b1, wih0, whh0, bih0, bhh0,
                       wih1, whh1, bih1, bhh1, w2, b2, out, Bn);
}

// Round 6
// 330.987 us; speedup vs baseline: 4.1507x; 4.1507x over previous
//
#include <hip/hip_runtime.h>

// Fused: linear(12->1)+tanh -> LSTM(1->7) -> LSTM(7->7) -> linear(14->1)
// Round 6 = Round 5 resubmit (broker capacity failure, no signal).
// No inline asm (R4's per-iteration VGPR launder caused nondeterministic
// graph-replay divergence). Anti-LICM is structural: TWO identical weight
// copies in LDS, base=(t&1)*1024 -> addresses vary per iteration, nothing to
// hoist, no spill. M=2 batch elements per thread so each broadcast ds_read_b128
// feeds two FMA chains (DS pipe was the R4 bottleneck: ~171 reads/t/wave).

static __device__ __forceinline__ float fexp2(float x) { return __builtin_amdgcn_exp2f(x); }
static __device__ __forceinline__ float frcp(float x)  { return __builtin_amdgcn_rcpf(x); }
static __device__ __forceinline__ float sigm(float x)  {
    return frcp(1.0f + fexp2(-1.4426950408889634f * x));
}
static __device__ __forceinline__ float tanhh(float x) {
    return 1.0f - 2.0f * frcp(fexp2(2.8853900817779268f * x) + 1.0f);
}

#define TT 14
#define FF 12
#define HH 7
#define NG 28   // 4*HH gate rows, r = gate*7 + j  (i,f,g,o)

// LDS float-index offsets within one copy (all multiples of 4 -> 16B aligned)
#define OFF_W1    0     // 12 floats (+4 pad)
#define OFF_WIH0  16    // 28
#define OFF_B0    44    // 28 (bih0+bhh0)
#define OFF_WHH0  72    // 196, transposed: [k][r] = whh0[r*7+k]
#define OFF_WIH1  268   // 196, transposed
#define OFF_WHH1  464   // 196, transposed
#define OFF_B1    660   // 28 (bih1+bhh1)
#define OFF_W2    688   // 14
#define OFF_SC    702   // b1, b2 scalars
#define CSZ       704
#define SMCOPY    1024  // float stride between the two identical copies
#define SMEM_F    (SMCOPY + CSZ)

#define LD4(off) (*reinterpret_cast<const float4*>(sm + base + (off)))

// gate math for one element; all indices compile-time after inlining
static __device__ __forceinline__ void gates(const float* z, float* c, float* h) {
#pragma unroll
    for (int j = 0; j < HH; ++j) {
        const float ii = sigm(z[j]);
        const float ff = sigm(z[HH + j]);
        const float gg = tanhh(z[2 * HH + j]);
        const float oo = sigm(z[3 * HH + j]);
        c[j] = ff * c[j] + ii * gg;
        h[j] = oo * tanhh(c[j]);
    }
}

__global__ __launch_bounds__(256)
void lstm_fused_kernel(const float* __restrict__ x,
                       const float* __restrict__ w1,   const float* __restrict__ b1,
                       const float* __restrict__ wih0, const float* __restrict__ whh0,
                       const float* __restrict__ bih0, const float* __restrict__ bhh0,
                       const float* __restrict__ wih1, const float* __restrict__ whh1,
                       const float* __restrict__ bih1, const float* __restrict__ bhh1,
                       const float* __restrict__ w2,   const float* __restrict__ b2,
                       float* __restrict__ out, int Bn2)
{
    __shared__ __align__(16) float sm[SMEM_F];
    const int tid = threadIdx.x;

    // ---- stage weights into BOTH copies (transpose hidden mats to [k][r]) ----
#pragma unroll
    for (int cpy = 0; cpy < 2; ++cpy) {
        float* s = sm + cpy * SMCOPY;
        if (tid < 196) {
            const int k = tid / 28, r = tid % 28;
            s[OFF_WHH0 + tid] = whh0[r * 7 + k];
            s[OFF_WIH1 + tid] = wih1[r * 7 + k];
            s[OFF_WHH1 + tid] = whh1[r * 7 + k];
        }
        if (tid < NG) {
            s[OFF_WIH0 + tid] = wih0[tid];
            s[OFF_B0 + tid]   = bih0[tid] + bhh0[tid];
            s[OFF_B1 + tid]   = bih1[tid] + bhh1[tid];
        }
        if (tid < FF)      s[OFF_W1 + tid] = w1[tid];
        if (tid < 2 * HH)  s[OFF_W2 + tid] = w2[tid];
        if (tid == 0) { s[OFF_SC] = b1[0]; s[OFF_SC + 1] = b2[0]; }
    }
    __syncthreads();

    const int p = blockIdx.x * blockDim.x + tid;   // pair index
    if (p >= Bn2) return;
    // two adjacent batch elements per thread (B is even: 262144)
    const float4* xvA = reinterpret_cast<const float4*>(x + (size_t)(2 * p) * (TT * FF));
    const float4* xvB = xvA + (TT * FF / 4);

    float h0a[HH], c0a[HH], h1a[HH], c1a[HH];
    float h0b[HH], c0b[HH], h1b[HH], c1b[HH];
#pragma unroll
    for (int j = 0; j < HH; ++j) {
        h0a[j] = 0.f; c0a[j] = 0.f; h1a[j] = 0.f; c1a[j] = 0.f;
        h0b[j] = 0.f; c0b[j] = 0.f; h1b[j] = 0.f; c1b[j] = 0.f;
    }

    const float b1s = sm[OFF_SC], b2s = sm[OFF_SC + 1];
    float4 xA0 = xvA[0], xA1 = xvA[1], xA2 = xvA[2];
    float4 xB0 = xvB[0], xB1 = xvB[1], xB2 = xvB[2];

#pragma unroll 1
    for (int t = 0; t < TT; ++t) {
        const int base = (t & 1) * SMCOPY;   // varies per iter -> no LICM of LDS reads

        // 1-deep prefetch of next timestep's x (wraps to 0 on last iter; in-bounds)
        const int tn = (t < TT - 1) ? 3 * (t + 1) : 0;
        float4 nA0 = xvA[tn], nA1 = xvA[tn + 1], nA2 = xvA[tn + 2];
        float4 nB0 = xvB[tn], nB1 = xvB[tn + 1], nB2 = xvB[tn + 2];

        // ---- linear_1 + tanh for both elements ----
        float acc0 = b1s, acc1 = b1s;
        {
            float4 wa = LD4(OFF_W1 + 0), wb = LD4(OFF_W1 + 4), wc = LD4(OFF_W1 + 8);
            acc0 = fmaf(xA0.x, wa.x, acc0); acc0 = fmaf(xA0.y, wa.y, acc0);
            acc0 = fmaf(xA0.z, wa.z, acc0); acc0 = fmaf(xA0.w, wa.w, acc0);
            acc0 = fmaf(xA1.x, wb.x, acc0); acc0 = fmaf(xA1.y, wb.y, acc0);
            acc0 = fmaf(xA1.z, wb.z, acc0); acc0 = fmaf(xA1.w, wb.w, acc0);
            acc0 = fmaf(xA2.x, wc.x, acc0); acc0 = fmaf(xA2.y, wc.y, acc0);
            acc0 = fmaf(xA2.z, wc.z, acc0); acc0 = fmaf(xA2.w, wc.w, acc0);
            acc1 = fmaf(xB0.x, wa.x, acc1); acc1 = fmaf(xB0.y, wa.y, acc1);
            acc1 = fmaf(xB0.z, wa.z, acc1); acc1 = fmaf(xB0.w, wa.w, acc1);
            acc1 = fmaf(xB1.x, wb.x, acc1); acc1 = fmaf(xB1.y, wb.y, acc1);
            acc1 = fmaf(xB1.z, wb.z, acc1); acc1 = fmaf(xB1.w, wb.w, acc1);
            acc1 = fmaf(xB2.x, wc.x, acc1); acc1 = fmaf(xB2.y, wc.y, acc1);
            acc1 = fmaf(xB2.z, wc.z, acc1); acc1 = fmaf(xB2.w, wc.w, acc1);
        }
        const float xt0 = tanhh(acc0), xt1 = tanhh(acc1);

        float z0[NG], z1[NG];

        // ---- LSTM layer 0: z = b0 + xt*wih0 + h0 @ whh0^T ----
#pragma unroll
        for (int q = 0; q < 7; ++q) {
            float4 bq = LD4(OFF_B0 + 4 * q);
            float4 wq = LD4(OFF_WIH0 + 4 * q);
            z0[4*q+0] = fmaf(xt0, wq.x, bq.x); z1[4*q+0] = fmaf(xt1, wq.x, bq.x);
            z0[4*q+1] = fmaf(xt0, wq.y, bq.y); z1[4*q+1] = fmaf(xt1, wq.y, bq.y);
            z0[4*q+2] = fmaf(xt0, wq.z, bq.z); z1[4*q+2] = fmaf(xt1, wq.z, bq.z);
            z0[4*q+3] = fmaf(xt0, wq.w, bq.w); z1[4*q+3] = fmaf(xt1, wq.w, bq.w);
        }
#pragma unroll
        for (int k = 0; k < HH; ++k) {
            const float ka = h0a[k], kb = h0b[k];
#pragma unroll
            for (int q = 0; q < 7; ++q) {
                float4 wq = LD4(OFF_WHH0 + 28 * k + 4 * q);
                z0[4*q+0] = fmaf(ka, wq.x, z0[4*q+0]); z1[4*q+0] = fmaf(kb, wq.x, z1[4*q+0]);
                z0[4*q+1] = fmaf(ka, wq.y, z0[4*q+1]); z1[4*q+1] = fmaf(kb, wq.y, z1[4*q+1]);
                z0[4*q+2] = fmaf(ka, wq.z, z0[4*q+2]); z1[4*q+2] = fmaf(kb, wq.z, z1[4*q+2]);
                z0[4*q+3] = fmaf(ka, wq.w, z0[4*q+3]); z1[4*q+3] = fmaf(kb, wq.w, z1[4*q+3]);
            }
        }
        gates(z0, c0a, h0a);
        gates(z1, c0b, h0b);

        // ---- LSTM layer 1: z = b1 + h0_new @ wih1^T + h1 @ whh1^T ----
#pragma unroll
        for (int q = 0; q < 7; ++q) {
            float4 bq = LD4(OFF_B1 + 4 * q);
            z0[4*q+0] = bq.x; z1[4*q+0] = bq.x;
            z0[4*q+1] = bq.y; z1[4*q+1] = bq.y;
            z0[4*q+2] = bq.z; z1[4*q+2] = bq.z;
            z0[4*q+3] = bq.w; z1[4*q+3] = bq.w;
        }
#pragma unroll
        for (int k = 0; k < HH; ++k) {
            const float ia = h0a[k], ib = h0b[k];
            const float ja = h1a[k], jb = h1b[k];
#pragma unroll
            for (int q = 0; q < 7; ++q) {
                float4 wq = LD4(OFF_WIH1 + 28 * k + 4 * q);
                float4 vq = LD4(OFF_WHH1 + 28 * k + 4 * q);
                z0[4*q+0] = fmaf(ia, wq.x, fmaf(ja, vq.x, z0[4*q+0]));
                z1[4*q+0] = fmaf(ib, wq.x, fmaf(jb, vq.x, z1[4*q+0]));
                z0[4*q+1] = fmaf(ia, wq.y, fmaf(ja, vq.y, z0[4*q+1]));
                z1[4*q+1] = fmaf(ib, wq.y, fmaf(jb, vq.y, z1[4*q+1]));
                z0[4*q+2] = fmaf(ia, wq.z, fmaf(ja, vq.z, z0[4*q+2]));
                z1[4*q+2] = fmaf(ib, wq.z, fmaf(jb, vq.z, z1[4*q+2]));
                z0[4*q+3] = fmaf(ia, wq.w, fmaf(ja, vq.w, z0[4*q+3]));
                z1[4*q+3] = fmaf(ib, wq.w, fmaf(jb, vq.w, z1[4*q+3]));
            }
        }
        gates(z0, c1a, h1a);
        gates(z1, c1b, h1b);

        xA0 = nA0; xA1 = nA1; xA2 = nA2;
        xB0 = nB0; xB1 = nB1; xB2 = nB2;
    }

    // ---- linear_2 on concat(h0_final, h1_final), coalesced float2 store ----
    float r0 = b2s, r1 = b2s;
#pragma unroll
    for (int j = 0; j < HH; ++j) {
        const float wj = sm[OFF_W2 + j];
        r0 = fmaf(h0a[j], wj, r0); r1 = fmaf(h0b[j], wj, r1);
    }
#pragma unroll
    for (int j = 0; j < HH; ++j) {
        const float wj = sm[OFF_W2 + HH + j];
        r0 = fmaf(h1a[j], wj, r0); r1 = fmaf(h1b[j], wj, r1);
    }
    *reinterpret_cast<float2*>(out + 2 * (size_t)p) = make_float2(r0, r1);
}

extern "C" void kernel_launch(void* const* d_in, const int* in_sizes, int n_in,
                              void* d_out, int out_size, void* d_ws, size_t ws_size,
                              hipStream_t stream)
{
    const float* x    = (const float*)d_in[0];
    const float* w1   = (const float*)d_in[1];
    const float* b1   = (const float*)d_in[2];
    const float* wih0 = (const float*)d_in[3];
    const float* whh0 = (const float*)d_in[4];
    const float* bih0 = (const float*)d_in[5];
    const float* bhh0 = (const float*)d_in[6];
    const float* wih1 = (const float*)d_in[7];
    const float* whh1 = (const float*)d_in[8];
    const float* bih1 = (const float*)d_in[9];
    const float* bhh1 = (const float*)d_in[10];
    const float* w2   = (const float*)d_in[11];
    const float* b2   = (const float*)d_in[12];
    float* out = (float*)d_out;

    const int Bn  = in_sizes[0] / (TT * FF);   // 262144 (even)
    const int Bn2 = Bn >> 1;                   // element pairs per thread
    dim3 grid((Bn2 + 255) / 256), block(256);
    hipLaunchKernelGGL(lstm_fused_kernel, grid, block, 0, stream,
                       x, w1, b1, wih0, whh0, bih0, bhh0,
                       wih1, whh1, bih1, bhh1, w2, b2, out, Bn2);
}